// Round 4
// baseline (148.811 us; speedup 1.0000x reference)
//
#include <hip/hip_runtime.h>
#include <float.h>

#define B_CONST 8
#define GROUPS 4          // ref-dim split across blocks (combined in fused final)

typedef float v2f __attribute__((ext_vector_type(2)));

// Agent-scope load: emits sc0/sc1 (bypasses L1 + non-coherent per-XCD L2) so the
// fused final reduce sees partials written by blocks on other XCDs.
__device__ __forceinline__ float coh_load(const float* p) {
    return __hip_atomic_load(p, __ATOMIC_RELAXED, __HIP_MEMORY_SCOPE_AGENT);
}

// comm layout (uints): [0..7] per-batch max bits, [8] global ticket,
//                      [9..24] per-(dir,b) block-done tickets.
// Pack (x,y,z) -> float4(x,y,z,|p|^2), coalesced dwordx4 stores; also zero comm.
__global__ void hd_pack(const float* __restrict__ p1, const float* __restrict__ p2,
                        float4* __restrict__ o1, float4* __restrict__ o2,
                        unsigned int* __restrict__ comm, int n1, int n2) {
    int i = blockIdx.x * blockDim.x + threadIdx.x;
    if (blockIdx.x == 0 && threadIdx.x < 25) comm[threadIdx.x] = 0u;
    const float* src; float4* dst; int idx;
    if (i < n1)           { src = p1; dst = o1; idx = i; }
    else if (i < n1 + n2) { src = p2; dst = o2; idx = i - n1; }
    else return;
    size_t s = 3 * (size_t)idx;
    float x = src[s], y = src[s + 1], z = src[s + 2];
    dst[idx] = make_float4(x, y, z, fmaf(x, x, fmaf(y, y, z * z)));
}

// Block = 512 queries x 8 wave-chunks of one ref group. Each thread holds Q=8
// queries (4 packed pairs); each uniform ref point (16B s_load, SGPR broadcast)
// feeds 16 packed VALU ops. 8 wave-partials combined in LDS, per-(group,query)
// mins stored coalesced (no atomics). Last block per (dir,b) (ticket) reduces
// that slice; global ticket 15 sums into out[0].
__global__ __launch_bounds__(512) void hd_nnmax(
    const float4* __restrict__ qpt1, const float4* __restrict__ qpt2,
    float* __restrict__ part, unsigned int* __restrict__ comm,
    float* __restrict__ out, int N, int M, int blocksDir0) {
    int blk = blockIdx.x;
    const float4* q; const float4* r; int QN, RM, dir;
    if (blk < blocksDir0) { q = qpt1; r = qpt2; QN = N; RM = M; dir = 0; }
    else { blk -= blocksDir0; q = qpt2; r = qpt1; QN = M; RM = N; dir = 1; }

    int qblocks = QN >> 9;                       // 512 queries per block
    int perB = qblocks * GROUPS;
    int b    = blk / perB;
    int rem  = blk - b * perB;
    int qblk = rem / GROUPS;
    int g    = rem - qblk * GROUPS;

    int l = threadIdx.x & 63;
    int w = __builtin_amdgcn_readfirstlane((int)(threadIdx.x >> 6));   // 0..7

    // 8 queries per thread: slot s -> query qblk*512 + s*64 + l (coalesced).
    const float4* qb = q + (size_t)b * QN + ((size_t)qblk << 9);
    float4 qv[8];
    #pragma unroll
    for (int s = 0; s < 8; ++s) qv[s] = qb[s * 64 + l];
    v2f NX[4], NY[4], NZ[4], MN[4];
    #pragma unroll
    for (int p = 0; p < 4; ++p) {
        NX[p] = (v2f){ -2.0f * qv[2*p].x, -2.0f * qv[2*p+1].x };
        NY[p] = (v2f){ -2.0f * qv[2*p].y, -2.0f * qv[2*p+1].y };
        NZ[p] = (v2f){ -2.0f * qv[2*p].z, -2.0f * qv[2*p+1].z };
        MN[p] = (v2f){ FLT_MAX, FLT_MAX };
    }

    // This wave's ref chunk: RM/32 points (GROUPS groups x 8 waves).
    int cnt = RM >> 5;
    const float4* rb = r + (size_t)b * RM + (size_t)g * (RM >> 2) + (size_t)w * cnt;

    #pragma unroll 8
    for (int j = 0; j < cnt; ++j) {
        float4 rf = rb[j];                      // wave-uniform -> s_load_dwordx4
        v2f rx = (v2f){ rf.x, rf.x };
        v2f ry = (v2f){ rf.y, rf.y };
        v2f rz = (v2f){ rf.z, rf.z };
        v2f rw = (v2f){ rf.w, rf.w };
        #pragma unroll
        for (int p = 0; p < 4; ++p) {
            v2f a = __builtin_elementwise_fma(NX[p], rx, rw);
            a = __builtin_elementwise_fma(NY[p], ry, a);
            a = __builtin_elementwise_fma(NZ[p], rz, a);
            MN[p] = __builtin_elementwise_min(MN[p], a);
        }
    }

    // Combine the 8 wave-partials per query in LDS.
    __shared__ float red[4096];                 // [wave][query-in-block]
    #pragma unroll
    for (int p = 0; p < 4; ++p) {
        red[(w << 9) + (2*p)     * 64 + l] = MN[p].x;
        red[(w << 9) + (2*p + 1) * 64 + l] = MN[p].y;
    }
    __syncthreads();
    int t = threadIdx.x;                        // query-in-block index
    float m = red[t];
    #pragma unroll
    for (int ww = 1; ww < 8; ++ww) m = fminf(m, red[(ww << 9) + t]);
    float dist = fmaxf(qb[t].w + m, 0.0f);      // true min over this ref group

    // Coalesced partial store: part[dir][g][b][q].
    size_t dirOff = dir ? (size_t)GROUPS * B_CONST * N : 0;
    float* pb = part + dirOff + ((size_t)g * B_CONST + b) * QN;
    pb[((size_t)qblk << 9) + t] = dist;

    // Decoupled ticket: last block of this (dir,b) slice does the final reduce.
    __threadfence();
    __syncthreads();
    __shared__ unsigned int sTicket;
    int db = dir * B_CONST + b;
    if (threadIdx.x == 0) sTicket = atomicAdd(&comm[9 + db], 1u);
    __syncthreads();
    if (sTicket + 1u != (unsigned int)perB) return;

    // Final reduce for (dir,b): min over GROUPS partials, max over QN queries.
    const float* fb = part + dirOff + (size_t)b * QN;
    size_t gs = (size_t)B_CONST * QN;
    float mx = 0.0f;
    for (int qq = threadIdx.x; qq < QN; qq += 512) {
        float mm = coh_load(fb + qq);
        #pragma unroll
        for (int gg = 1; gg < GROUPS; ++gg)
            mm = fminf(mm, coh_load(fb + gg * gs + qq));
        mx = fmaxf(mx, mm);
    }
    #pragma unroll
    for (int off = 32; off > 0; off >>= 1)
        mx = fmaxf(mx, __shfl_down(mx, off, 64));
    __shared__ float wred[8];
    if (l == 0) wred[w] = mx;
    __syncthreads();
    if (threadIdx.x == 0) {
        #pragma unroll
        for (int ww = 1; ww < 8; ++ww) mx = fmaxf(mx, wred[ww]);
        atomicMax(&comm[b], __float_as_uint(mx));   // max over both directions
        __threadfence();
        unsigned int t2 = atomicAdd(&comm[8], 1u);
        if (t2 == 15u) {                            // last of 16 (dir,b) slices
            float s = 0.0f;
            for (int bb = 0; bb < B_CONST; ++bb)
                s += __uint_as_float(atomicMax(&comm[bb], 0u));  // coherent read
            out[0] = s;
        }
    }
}

extern "C" void kernel_launch(void* const* d_in, const int* in_sizes, int n_in,
                              void* d_out, int out_size, void* d_ws, size_t ws_size,
                              hipStream_t stream) {
    const float* p1 = (const float*)d_in[0];
    const float* p2 = (const float*)d_in[1];
    const int B = B_CONST;
    int N = in_sizes[0] / (3 * B);
    int M = in_sizes[1] / (3 * B);
    int n1 = B * N, n2 = B * M;

    char* ws = (char*)d_ws;
    float4* qpt1 = (float4*)ws;
    float4* qpt2 = (float4*)(ws + (size_t)n1 * sizeof(float4));
    float* part  = (float*)(ws + (size_t)(n1 + n2) * sizeof(float4));
    unsigned int* comm = (unsigned int*)(part + (size_t)GROUPS * (n1 + n2));

    int packBlocks = (n1 + n2 + 255) / 256;
    hd_pack<<<packBlocks, 256, 0, stream>>>(p1, p2, qpt1, qpt2, comm, n1, n2);

    int blocksDir0 = B * (N >> 9) * GROUPS;
    int blocksDir1 = B * (M >> 9) * GROUPS;
    hd_nnmax<<<blocksDir0 + blocksDir1, 512, 0, stream>>>(
        qpt1, qpt2, part, comm, (float*)d_out, N, M, blocksDir0);
}

// Round 5
// 85.230 us; speedup vs baseline: 1.7460x; 1.7460x over previous
//
#include <hip/hip_runtime.h>
#include <float.h>

#define B_CONST 8
#define GROUPS 16         // ref-dim split across blocks (combined in hd_final)
#define QSPLIT 8          // query-dim split of the final reduce

typedef float v2f __attribute__((ext_vector_type(2)));

// comm layout (uints): [0..7] per-batch max bits, [8] global ticket.
// Pack (x,y,z) -> float4(x,y,z,|p|^2), coalesced dwordx4 stores; also zero comm.
__global__ void hd_pack(const float* __restrict__ p1, const float* __restrict__ p2,
                        float4* __restrict__ o1, float4* __restrict__ o2,
                        unsigned int* __restrict__ comm, int n1, int n2) {
    int i = blockIdx.x * blockDim.x + threadIdx.x;
    if (blockIdx.x == 0 && threadIdx.x < 9) comm[threadIdx.x] = 0u;
    const float* src; float4* dst; int idx;
    if (i < n1)           { src = p1; dst = o1; idx = i; }
    else if (i < n1 + n2) { src = p2; dst = o2; idx = i - n1; }
    else return;
    size_t s = 3 * (size_t)idx;
    float x = src[s], y = src[s + 1], z = src[s + 2];
    dst[idx] = make_float4(x, y, z, fmaf(x, x, fmaf(y, y, z * z)));
}

// Block = 1024 queries (64 lanes x Q=16 per thread) x 4 wave-chunks of one ref
// group. Each uniform 16B ref s_load feeds 32 packed VALU ops (8 pairs x
// 3 pk_fma + pk_min) -> 64 issue-cycles per load; 4 waves/SIMD hide the ~200cyc
// SMEM latency. 4 wave-partials combined in LDS, plain coalesced partial store
// per (group, query). No fences, no atomics in this kernel.
__global__ __launch_bounds__(256) void hd_nnmax(
    const float4* __restrict__ qpt1, const float4* __restrict__ qpt2,
    float* __restrict__ part, int N, int M, int blocksDir0) {
    int blk = blockIdx.x;
    const float4* q; const float4* r; int QN, RM, dir;
    if (blk < blocksDir0) { q = qpt1; r = qpt2; QN = N; RM = M; dir = 0; }
    else { blk -= blocksDir0; q = qpt2; r = qpt1; QN = M; RM = N; dir = 1; }

    int qblocks = QN >> 10;                      // 1024 queries per block
    int perB = qblocks * GROUPS;
    int b    = blk / perB;
    int rem  = blk - b * perB;
    int qblk = rem / GROUPS;
    int g    = rem - qblk * GROUPS;

    int l = threadIdx.x & 63;
    int w = __builtin_amdgcn_readfirstlane((int)(threadIdx.x >> 6));   // 0..3

    __shared__ float red[4096];                  // [wave][query-in-block]
    __shared__ float qw_s[1024];                 // |q|^2 per query-in-block

    // 16 queries per thread: slot s -> query qblk*1024 + s*64 + l (coalesced).
    const float4* qb = q + (size_t)b * QN + ((size_t)qblk << 10);
    v2f NX[8], NY[8], NZ[8], MN[8];
    #pragma unroll
    for (int p = 0; p < 8; ++p) {
        float4 q0 = qb[(2 * p) * 64 + l];
        float4 q1 = qb[(2 * p + 1) * 64 + l];
        NX[p] = (v2f){ -2.0f * q0.x, -2.0f * q1.x };
        NY[p] = (v2f){ -2.0f * q0.y, -2.0f * q1.y };
        NZ[p] = (v2f){ -2.0f * q0.z, -2.0f * q1.z };
        MN[p] = (v2f){ FLT_MAX, FLT_MAX };
        if (w == 0) {                            // one wave stashes |q|^2
            qw_s[(2 * p) * 64 + l]     = q0.w;
            qw_s[(2 * p + 1) * 64 + l] = q1.w;
        }
    }

    // This wave's ref chunk: RM/64 points (GROUPS groups x 4 waves).
    int cnt = RM >> 6;
    const float4* rb = r + (size_t)b * RM + (size_t)(g * 4 + w) * cnt;

    #pragma unroll 4
    for (int j = 0; j < cnt; ++j) {
        float4 rf = rb[j];                       // wave-uniform -> s_load_dwordx4
        v2f rx = (v2f){ rf.x, rf.x };
        v2f ry = (v2f){ rf.y, rf.y };
        v2f rz = (v2f){ rf.z, rf.z };
        v2f rw = (v2f){ rf.w, rf.w };
        #pragma unroll
        for (int p = 0; p < 8; ++p) {
            v2f a = __builtin_elementwise_fma(NX[p], rx, rw);
            a = __builtin_elementwise_fma(NY[p], ry, a);
            a = __builtin_elementwise_fma(NZ[p], rz, a);
            MN[p] = __builtin_elementwise_min(MN[p], a);
        }
    }

    // Combine the 4 wave-partials per query in LDS.
    #pragma unroll
    for (int p = 0; p < 8; ++p) {
        red[(w << 10) + (2 * p) * 64 + l]     = MN[p].x;
        red[(w << 10) + (2 * p + 1) * 64 + l] = MN[p].y;
    }
    __syncthreads();

    // part[dir][g][b][query]: plain coalesced stores, combined in hd_final.
    size_t dirOff = dir ? (size_t)GROUPS * B_CONST * N : 0;
    float* pb = part + dirOff + ((size_t)g * B_CONST + b) * QN + ((size_t)qblk << 10);
    for (int t = threadIdx.x; t < 1024; t += 256) {
        float m = fminf(fminf(red[t], red[1024 + t]),
                        fminf(red[2048 + t], red[3072 + t]));
        pb[t] = fmaxf(qw_s[t] + m, 0.0f);
    }
}

// 128 blocks: one per (dir, b, query-slice). min over GROUPS partials, max over
// the query slice, atomicMax into comm[b]; global ticket 127 sums into out[0].
// Cross-kernel visibility of `part` is free (kernel-boundary release/acquire).
__global__ __launch_bounds__(256) void hd_final(
    const float* __restrict__ part, unsigned int* __restrict__ comm,
    float* __restrict__ out, int N, int M) {
    int db  = blockIdx.x >> 3;                  // 0..15
    int qs  = blockIdx.x & (QSPLIT - 1);
    int dir = db >> 3;
    int b   = db & 7;
    int QN  = dir ? M : N;
    size_t dirOff = dir ? (size_t)GROUPS * B_CONST * N : 0;
    const float* fb = part + dirOff + (size_t)b * QN;
    size_t gs = (size_t)B_CONST * QN;

    int span = QN / QSPLIT;
    int q0 = qs * span;
    float mx = 0.0f;
    for (int qq = q0 + threadIdx.x; qq < q0 + span; qq += 256) {
        float mm = fb[qq];
        #pragma unroll
        for (int gg = 1; gg < GROUPS; ++gg)
            mm = fminf(mm, fb[(size_t)gg * gs + qq]);
        mx = fmaxf(mx, mm);
    }
    #pragma unroll
    for (int off = 32; off > 0; off >>= 1)
        mx = fmaxf(mx, __shfl_down(mx, off, 64));
    __shared__ float wred[4];
    int l = threadIdx.x & 63, w = threadIdx.x >> 6;
    if (l == 0) wred[w] = mx;
    __syncthreads();
    if (threadIdx.x == 0) {
        mx = fmaxf(fmaxf(wred[0], wred[1]), fmaxf(wred[2], wred[3]));
        atomicMax(&comm[b], __float_as_uint(mx));   // covers both dirs + slices
        __threadfence();
        unsigned int t2 = atomicAdd(&comm[8], 1u);
        if (t2 == (unsigned int)(16 * QSPLIT - 1)) {
            float s = 0.0f;
            for (int bb = 0; bb < B_CONST; ++bb)
                s += __uint_as_float(atomicMax(&comm[bb], 0u));  // coherent read
            out[0] = s;
        }
    }
}

extern "C" void kernel_launch(void* const* d_in, const int* in_sizes, int n_in,
                              void* d_out, int out_size, void* d_ws, size_t ws_size,
                              hipStream_t stream) {
    const float* p1 = (const float*)d_in[0];
    const float* p2 = (const float*)d_in[1];
    const int B = B_CONST;
    int N = in_sizes[0] / (3 * B);
    int M = in_sizes[1] / (3 * B);
    int n1 = B * N, n2 = B * M;

    char* ws = (char*)d_ws;
    float4* qpt1 = (float4*)ws;
    float4* qpt2 = (float4*)(ws + (size_t)n1 * sizeof(float4));
    float* part  = (float*)(ws + (size_t)(n1 + n2) * sizeof(float4));
    unsigned int* comm = (unsigned int*)(part + (size_t)GROUPS * (n1 + n2));

    int packBlocks = (n1 + n2 + 255) / 256;
    hd_pack<<<packBlocks, 256, 0, stream>>>(p1, p2, qpt1, qpt2, comm, n1, n2);

    int blocksDir0 = B * (N >> 10) * GROUPS;
    int blocksDir1 = B * (M >> 10) * GROUPS;
    hd_nnmax<<<blocksDir0 + blocksDir1, 256, 0, stream>>>(
        qpt1, qpt2, part, N, M, blocksDir0);

    hd_final<<<16 * QSPLIT, 256, 0, stream>>>(part, comm, (float*)d_out, N, M);
}

// Round 6
// 83.386 us; speedup vs baseline: 1.7846x; 1.0221x over previous
//
#include <hip/hip_runtime.h>
#include <float.h>

#define B_CONST 8
#define GROUPS 16         // ref-dim split across blocks (combined in hd_final)
#define QSPLIT 8          // query-dim split of the final reduce

typedef float v2f __attribute__((ext_vector_type(2)));

// Pack refs into SoA point-pairs with -2 prefolded: pair j (points 2j,2j+1) ->
// [-2x0,-2x1 | -2y0,-2y1 | -2z0,-2z1 | w0,w1]  (w=|p|^2 unscaled), 32B/pair.
// Hot loop then s_loads each pair and feeds v_pk_fma_f32 with SGPR-pair
// operands directly -- zero per-point broadcast movs. Also zeroes comm[0..8].
__global__ void hd_pack(const float* __restrict__ p1, const float* __restrict__ p2,
                        float* __restrict__ o1, float* __restrict__ o2,
                        unsigned int* __restrict__ comm, int n1, int n2) {
    int i = blockIdx.x * blockDim.x + threadIdx.x;
    if (blockIdx.x == 0 && threadIdx.x < 9) comm[threadIdx.x] = 0u;
    const float* src; float* dst; int idx;
    if (i < n1)           { src = p1; dst = o1; idx = i; }
    else if (i < n1 + n2) { src = p2; dst = o2; idx = i - n1; }
    else return;
    size_t s = 3 * (size_t)idx;
    float x = src[s], y = src[s + 1], z = src[s + 2];
    float w = fmaf(x, x, fmaf(y, y, z * z));
    float* base = dst + (size_t)(idx >> 1) * 8 + (idx & 1);
    base[0] = -2.0f * x; base[2] = -2.0f * y; base[4] = -2.0f * z; base[6] = w;
}

// Block = 512 queries (64 lanes x Q=8) x 4 wave-chunks of one ref group.
// Per thread: 8 queries as {q,q} VGPR pairs (built once). Per 2 ref points:
// one uniform 32B s_load; per query 3 v_pk_fma_f32 (SGPR-pair ref operand) +
// 2 v_min -- no per-point broadcasts. 4 wave-partials combined in LDS, plain
// coalesced partial stores (no atomics, no fences).
__global__ __launch_bounds__(256) void hd_nnmax(
    const float* __restrict__ p1raw, const float* __restrict__ p2raw,
    const float* __restrict__ pk1, const float* __restrict__ pk2,
    float* __restrict__ part, int N, int M, int blocksDir0) {
    int blk = blockIdx.x;
    const float* qraw; const float* rpk; int QN, RM, dir;
    if (blk < blocksDir0) { qraw = p1raw; rpk = pk2; QN = N; RM = M; dir = 0; }
    else { blk -= blocksDir0; qraw = p2raw; rpk = pk1; QN = M; RM = N; dir = 1; }

    int qblocks = QN >> 9;                       // 512 queries per block
    int perB = qblocks * GROUPS;
    int b    = blk / perB;
    int rem  = blk - b * perB;
    int qblk = rem / GROUPS;
    int g    = rem - qblk * GROUPS;

    int l = threadIdx.x & 63;
    int w = __builtin_amdgcn_readfirstlane((int)(threadIdx.x >> 6));   // 0..3

    // 8 queries/thread from raw input: query s*64+l of this 512-query block.
    const float* qb = qraw + 3 * ((size_t)b * QN + ((size_t)qblk << 9));
    v2f QX[8], QY[8], QZ[8], MN[8];
    #pragma unroll
    for (int s = 0; s < 8; ++s) {
        int q = s * 64 + l;
        float x = qb[3 * q], y = qb[3 * q + 1], z = qb[3 * q + 2];
        QX[s] = (v2f){ x, x };
        QY[s] = (v2f){ y, y };
        QZ[s] = (v2f){ z, z };
        MN[s] = (v2f){ FLT_MAX, FLT_MAX };
    }

    // This wave's ref pairs: RM/2 pairs per (dir,b); GROUPS groups x 4 waves.
    int cnt = RM / (2 * GROUPS * 4);             // pairs per wave
    const v2f* rb = (const v2f*)rpk +
        ((size_t)b * (RM >> 1) + (size_t)(g * 4 + w) * cnt) * 4;

    #pragma unroll 4
    for (int j = 0; j < cnt; ++j) {
        v2f RX = rb[4 * j + 0];                  // uniform -> SGPR pairs
        v2f RY = rb[4 * j + 1];
        v2f RZ = rb[4 * j + 2];
        v2f RW = rb[4 * j + 3];
        #pragma unroll
        for (int s = 0; s < 8; ++s) {
            v2f a = __builtin_elementwise_fma(QX[s], RX, RW);
            a = __builtin_elementwise_fma(QY[s], RY, a);
            a = __builtin_elementwise_fma(QZ[s], RZ, a);
            MN[s] = __builtin_elementwise_min(MN[s], a);
        }
    }

    // Combine the 4 wave-partials per query in LDS.
    __shared__ float red[2048];                  // [wave][query-in-block]
    #pragma unroll
    for (int s = 0; s < 8; ++s)
        red[(w << 9) + s * 64 + l] = fminf(MN[s].x, MN[s].y);
    __syncthreads();

    // part[dir][g][b][query]: plain coalesced stores, combined in hd_final.
    size_t dirOff = dir ? (size_t)GROUPS * B_CONST * N : 0;
    float* pb = part + dirOff + ((size_t)g * B_CONST + b) * QN + ((size_t)qblk << 9);
    for (int t = threadIdx.x; t < 512; t += 256) {
        float m = fminf(fminf(red[t], red[512 + t]),
                        fminf(red[1024 + t], red[1536 + t]));
        float x = qb[3 * t], y = qb[3 * t + 1], z = qb[3 * t + 2];
        float w2 = fmaf(x, x, fmaf(y, y, z * z));
        pb[t] = fmaxf(w2 + m, 0.0f);             // min over this ref group
    }
}

// 128 blocks: one per (dir, b, query-slice). min over GROUPS partials, max over
// the query slice, atomicMax into comm[b]; global ticket 127 sums into out[0].
// Cross-kernel visibility of `part` is free (kernel-boundary release/acquire).
__global__ __launch_bounds__(256) void hd_final(
    const float* __restrict__ part, unsigned int* __restrict__ comm,
    float* __restrict__ out, int N, int M) {
    int db  = blockIdx.x >> 3;                  // 0..15
    int qs  = blockIdx.x & (QSPLIT - 1);
    int dir = db >> 3;
    int b   = db & 7;
    int QN  = dir ? M : N;
    size_t dirOff = dir ? (size_t)GROUPS * B_CONST * N : 0;
    const float* fb = part + dirOff + (size_t)b * QN;
    size_t gs = (size_t)B_CONST * QN;

    int span = QN / QSPLIT;
    int q0 = qs * span;
    float mx = 0.0f;
    for (int qq = q0 + threadIdx.x; qq < q0 + span; qq += 256) {
        float mm = fb[qq];
        #pragma unroll
        for (int gg = 1; gg < GROUPS; ++gg)
            mm = fminf(mm, fb[(size_t)gg * gs + qq]);
        mx = fmaxf(mx, mm);
    }
    #pragma unroll
    for (int off = 32; off > 0; off >>= 1)
        mx = fmaxf(mx, __shfl_down(mx, off, 64));
    __shared__ float wred[4];
    int l = threadIdx.x & 63, w = threadIdx.x >> 6;
    if (l == 0) wred[w] = mx;
    __syncthreads();
    if (threadIdx.x == 0) {
        mx = fmaxf(fmaxf(wred[0], wred[1]), fmaxf(wred[2], wred[3]));
        atomicMax(&comm[b], __float_as_uint(mx));   // covers both dirs + slices
        __threadfence();
        unsigned int t2 = atomicAdd(&comm[8], 1u);
        if (t2 == (unsigned int)(16 * QSPLIT - 1)) {
            float s = 0.0f;
            for (int bb = 0; bb < B_CONST; ++bb)
                s += __uint_as_float(atomicMax(&comm[bb], 0u));  // coherent read
            out[0] = s;
        }
    }
}

extern "C" void kernel_launch(void* const* d_in, const int* in_sizes, int n_in,
                              void* d_out, int out_size, void* d_ws, size_t ws_size,
                              hipStream_t stream) {
    const float* p1 = (const float*)d_in[0];
    const float* p2 = (const float*)d_in[1];
    const int B = B_CONST;
    int N = in_sizes[0] / (3 * B);
    int M = in_sizes[1] / (3 * B);
    int n1 = B * N, n2 = B * M;

    char* ws = (char*)d_ws;
    float* pk1 = (float*)ws;                                  // n1*4 floats
    float* pk2 = (float*)(ws + (size_t)n1 * 4 * sizeof(float));
    float* part = (float*)(ws + (size_t)(n1 + n2) * 4 * sizeof(float));
    unsigned int* comm = (unsigned int*)(part + (size_t)GROUPS * (n1 + n2));

    int packBlocks = (n1 + n2 + 255) / 256;
    hd_pack<<<packBlocks, 256, 0, stream>>>(p1, p2, pk1, pk2, comm, n1, n2);

    int blocksDir0 = B * (N >> 9) * GROUPS;
    int blocksDir1 = B * (M >> 9) * GROUPS;
    hd_nnmax<<<blocksDir0 + blocksDir1, 256, 0, stream>>>(
        p1, p2, pk1, pk2, part, N, M, blocksDir0);

    hd_final<<<16 * QSPLIT, 256, 0, stream>>>(part, comm, (float*)d_out, N, M);
}

// Round 7
// 82.865 us; speedup vs baseline: 1.7958x; 1.0063x over previous
//
#include <hip/hip_runtime.h>
#include <float.h>

#define B_CONST 8
#define GROUPS 16         // ref-dim split across blocks (combined in hd_final)
#define QSPLIT 8          // query-dim split of the final reduce

typedef float v2f __attribute__((ext_vector_type(2)));

// Pack refs into SoA point-pairs with -2 prefolded: pair j (points 2j,2j+1) ->
// [-2x0,-2x1 | -2y0,-2y1 | -2z0,-2z1 | w0,w1]  (w=|p|^2 unscaled), 32B/pair.
// Also zeroes comm[0..8].
__global__ void hd_pack(const float* __restrict__ p1, const float* __restrict__ p2,
                        float* __restrict__ o1, float* __restrict__ o2,
                        unsigned int* __restrict__ comm, int n1, int n2) {
    int i = blockIdx.x * blockDim.x + threadIdx.x;
    if (blockIdx.x == 0 && threadIdx.x < 9) comm[threadIdx.x] = 0u;
    const float* src; float* dst; int idx;
    if (i < n1)           { src = p1; dst = o1; idx = i; }
    else if (i < n1 + n2) { src = p2; dst = o2; idx = i - n1; }
    else return;
    size_t s = 3 * (size_t)idx;
    float x = src[s], y = src[s + 1], z = src[s + 2];
    float w = fmaf(x, x, fmaf(y, y, z * z));
    float* base = dst + (size_t)(idx >> 1) * 8 + (idx & 1);
    base[0] = -2.0f * x; base[2] = -2.0f * y; base[4] = -2.0f * z; base[6] = w;
}

// Block = 512 queries (64 lanes x Q=8) x one ref group of 256 points.
// The group's 128 packed pairs (4KB) are staged into LDS once (coalesced
// float4 per thread), then each of the 4 waves scans its 32-pair quarter at
// wave-uniform LDS addresses (broadcast reads: ~120cyc latency vs ~300cyc
// s_load, separate LDS pipe, deep lgkmcnt pipelining). Per pair per query:
// 3 v_pk_fma_f32 + v_pk_min. Cross-wave combine in LDS, plain coalesced
// partial stores (no atomics, no fences).
__global__ __launch_bounds__(256) void hd_nnmax(
    const float* __restrict__ p1raw, const float* __restrict__ p2raw,
    const float* __restrict__ pk1, const float* __restrict__ pk2,
    float* __restrict__ part, int N, int M, int blocksDir0) {
    int blk = blockIdx.x;
    const float* qraw; const float* rpk; int QN, RM, dir;
    if (blk < blocksDir0) { qraw = p1raw; rpk = pk2; QN = N; RM = M; dir = 0; }
    else { blk -= blocksDir0; qraw = p2raw; rpk = pk1; QN = M; RM = N; dir = 1; }

    int qblocks = QN >> 9;                       // 512 queries per block
    int perB = qblocks * GROUPS;
    int b    = blk / perB;
    int rem  = blk - b * perB;
    int qblk = rem / GROUPS;
    int g    = rem - qblk * GROUPS;

    int l = threadIdx.x & 63;
    int w = __builtin_amdgcn_readfirstlane((int)(threadIdx.x >> 6));   // 0..3

    __shared__ float ldsRef[1024];               // 128 pairs x 8 floats = 4KB
    __shared__ float red[2048];                  // [wave][query-in-block]

    // Stage this group's ref pairs: contiguous 4KB chunk, one float4/thread.
    int pairsPerGroup = RM / (2 * GROUPS);       // 128
    const float4* srcChunk = (const float4*)(rpk +
        ((size_t)b * (RM >> 1) + (size_t)g * pairsPerGroup) * 8);
    ((float4*)ldsRef)[threadIdx.x] = srcChunk[threadIdx.x];

    // 8 queries/thread from raw input: query s*64+l of this 512-query block.
    const float* qb = qraw + 3 * ((size_t)b * QN + ((size_t)qblk << 9));
    v2f QX[8], QY[8], QZ[8], MN[8];
    #pragma unroll
    for (int s = 0; s < 8; ++s) {
        int q = s * 64 + l;
        float x = qb[3 * q], y = qb[3 * q + 1], z = qb[3 * q + 2];
        QX[s] = (v2f){ x, x };
        QY[s] = (v2f){ y, y };
        QZ[s] = (v2f){ z, z };
        MN[s] = (v2f){ FLT_MAX, FLT_MAX };
    }
    __syncthreads();

    // Wave w scans pairs [w*32, w*32+32) from LDS (uniform address broadcast).
    const v2f* lp = (const v2f*)ldsRef + (size_t)(w * 32) * 4;
    #pragma unroll 4
    for (int j = 0; j < 32; ++j) {
        v2f RX = lp[4 * j + 0];
        v2f RY = lp[4 * j + 1];
        v2f RZ = lp[4 * j + 2];
        v2f RW = lp[4 * j + 3];
        #pragma unroll
        for (int s = 0; s < 8; ++s) {
            v2f a = __builtin_elementwise_fma(QX[s], RX, RW);
            a = __builtin_elementwise_fma(QY[s], RY, a);
            a = __builtin_elementwise_fma(QZ[s], RZ, a);
            MN[s] = __builtin_elementwise_min(MN[s], a);
        }
    }

    // Combine the 4 wave-partials per query in LDS.
    #pragma unroll
    for (int s = 0; s < 8; ++s)
        red[(w << 9) + s * 64 + l] = fminf(MN[s].x, MN[s].y);
    __syncthreads();

    // part[dir][g][b][query]: plain coalesced stores, combined in hd_final.
    size_t dirOff = dir ? (size_t)GROUPS * B_CONST * N : 0;
    float* pb = part + dirOff + ((size_t)g * B_CONST + b) * QN + ((size_t)qblk << 9);
    for (int t = threadIdx.x; t < 512; t += 256) {
        float m = fminf(fminf(red[t], red[512 + t]),
                        fminf(red[1024 + t], red[1536 + t]));
        float x = qb[3 * t], y = qb[3 * t + 1], z = qb[3 * t + 2];
        float w2 = fmaf(x, x, fmaf(y, y, z * z));
        pb[t] = fmaxf(w2 + m, 0.0f);             // min over this ref group
    }
}

// 128 blocks: one per (dir, b, query-slice). min over GROUPS partials, max over
// the query slice, atomicMax into comm[b]; global ticket 127 sums into out[0].
// Cross-kernel visibility of `part` is free (kernel-boundary release/acquire).
__global__ __launch_bounds__(256) void hd_final(
    const float* __restrict__ part, unsigned int* __restrict__ comm,
    float* __restrict__ out, int N, int M) {
    int db  = blockIdx.x >> 3;                  // 0..15
    int qs  = blockIdx.x & (QSPLIT - 1);
    int dir = db >> 3;
    int b   = db & 7;
    int QN  = dir ? M : N;
    size_t dirOff = dir ? (size_t)GROUPS * B_CONST * N : 0;
    const float* fb = part + dirOff + (size_t)b * QN;
    size_t gs = (size_t)B_CONST * QN;

    int span = QN / QSPLIT;
    int q0 = qs * span;
    float mx = 0.0f;
    for (int qq = q0 + threadIdx.x; qq < q0 + span; qq += 256) {
        float mm = fb[qq];
        #pragma unroll
        for (int gg = 1; gg < GROUPS; ++gg)
            mm = fminf(mm, fb[(size_t)gg * gs + qq]);
        mx = fmaxf(mx, mm);
    }
    #pragma unroll
    for (int off = 32; off > 0; off >>= 1)
        mx = fmaxf(mx, __shfl_down(mx, off, 64));
    __shared__ float wred[4];
    int l = threadIdx.x & 63, w = threadIdx.x >> 6;
    if (l == 0) wred[w] = mx;
    __syncthreads();
    if (threadIdx.x == 0) {
        mx = fmaxf(fmaxf(wred[0], wred[1]), fmaxf(wred[2], wred[3]));
        atomicMax(&comm[b], __float_as_uint(mx));   // covers both dirs + slices
        __threadfence();
        unsigned int t2 = atomicAdd(&comm[8], 1u);
        if (t2 == (unsigned int)(16 * QSPLIT - 1)) {
            float s = 0.0f;
            for (int bb = 0; bb < B_CONST; ++bb)
                s += __uint_as_float(atomicMax(&comm[bb], 0u));  // coherent read
            out[0] = s;
        }
    }
}

extern "C" void kernel_launch(void* const* d_in, const int* in_sizes, int n_in,
                              void* d_out, int out_size, void* d_ws, size_t ws_size,
                              hipStream_t stream) {
    const float* p1 = (const float*)d_in[0];
    const float* p2 = (const float*)d_in[1];
    const int B = B_CONST;
    int N = in_sizes[0] / (3 * B);
    int M = in_sizes[1] / (3 * B);
    int n1 = B * N, n2 = B * M;

    char* ws = (char*)d_ws;
    float* pk1 = (float*)ws;                                  // n1*4 floats
    float* pk2 = (float*)(ws + (size_t)n1 * 4 * sizeof(float));
    float* part = (float*)(ws + (size_t)(n1 + n2) * 4 * sizeof(float));
    unsigned int* comm = (unsigned int*)(part + (size_t)GROUPS * (n1 + n2));

    int packBlocks = (n1 + n2 + 255) / 256;
    hd_pack<<<packBlocks, 256, 0, stream>>>(p1, p2, pk1, pk2, comm, n1, n2);

    int blocksDir0 = B * (N >> 9) * GROUPS;
    int blocksDir1 = B * (M >> 9) * GROUPS;
    hd_nnmax<<<blocksDir0 + blocksDir1, 256, 0, stream>>>(
        p1, p2, pk1, pk2, part, N, M, blocksDir0);

    hd_final<<<16 * QSPLIT, 256, 0, stream>>>(part, comm, (float*)d_out, N, M);
}

// Round 8
// 82.623 us; speedup vs baseline: 1.8011x; 1.0029x over previous
//
#include <hip/hip_runtime.h>
#include <float.h>

#define B_CONST 8
#define GROUPS 8          // ref-dim split across blocks (combined in hd_final)
#define QSPLIT 8          // query-dim split of the final reduce

typedef float v2f __attribute__((ext_vector_type(2)));

// Single hot kernel, no separate pack pass. Block = 512 queries (64 lanes x
// Q=8) x one ref group of 512 points. The block stages its group's 512 raw
// refs into LDS as packed SoA pairs with -2 prefolded:
//   pair p -> [-2x0,-2x1 | -2y0,-2y1 | -2z0,-2z1 | w0,w1]   (8KB tile)
// then each of the 4 waves scans its 64-pair quarter at wave-uniform LDS
// addresses (broadcast reads). Per pair per query: 3 v_pk_fma_f32 + v_pk_min.
// Cross-wave combine reuses the tile LDS; plain coalesced partial stores.
// Block 0 also zeroes comm[0..8] (consumed only by hd_final, next graph node).
__global__ __launch_bounds__(256) void hd_nnmax(
    const float* __restrict__ p1raw, const float* __restrict__ p2raw,
    float* __restrict__ part, unsigned int* __restrict__ comm,
    int N, int M, int blocksDir0) {
    int blk = blockIdx.x;
    if (blk == 0 && threadIdx.x < 9) comm[threadIdx.x] = 0u;

    const float* qraw; const float* rraw; int QN, RM, dir;
    if (blk < blocksDir0) { qraw = p1raw; rraw = p2raw; QN = N; RM = M; dir = 0; }
    else { blk -= blocksDir0; qraw = p2raw; rraw = p1raw; QN = M; RM = N; dir = 1; }

    int qblocks = QN >> 9;                       // 512 queries per block
    int perB = qblocks * GROUPS;
    int b    = blk / perB;
    int rem  = blk - b * perB;
    int qblk = rem / GROUPS;
    int g    = rem - qblk * GROUPS;

    int l = threadIdx.x & 63;
    int w = __builtin_amdgcn_readfirstlane((int)(threadIdx.x >> 6));   // 0..3

    __shared__ float buf[2048];                  // tile (8KB), reused as red
    __shared__ float qw_s[512];                  // |q|^2 per query-in-block

    // Stage + pack this group's 512 refs: thread i packs pair i (refs 2i,2i+1).
    int refsPerGroup = RM / GROUPS;              // 512
    const float* rsrc = rraw + 3 * ((size_t)b * RM + (size_t)g * refsPerGroup);
    {
        int i = threadIdx.x;                     // pair index 0..255
        float x0 = rsrc[6*i],   y0 = rsrc[6*i+1], z0 = rsrc[6*i+2];
        float x1 = rsrc[6*i+3], y1 = rsrc[6*i+4], z1 = rsrc[6*i+5];
        float* t = buf + 8 * i;
        t[0] = -2.0f * x0; t[1] = -2.0f * x1;
        t[2] = -2.0f * y0; t[3] = -2.0f * y1;
        t[4] = -2.0f * z0; t[5] = -2.0f * z1;
        t[6] = fmaf(x0, x0, fmaf(y0, y0, z0 * z0));
        t[7] = fmaf(x1, x1, fmaf(y1, y1, z1 * z1));
    }

    // 8 queries/thread from raw input (q depends only on lane -> all 4 waves
    // load the same 512 queries, L1-served). Wave 0 stashes |q|^2.
    const float* qb = qraw + 3 * ((size_t)b * QN + ((size_t)qblk << 9));
    v2f QX[8], QY[8], QZ[8], MN[8];
    #pragma unroll
    for (int s = 0; s < 8; ++s) {
        int q = s * 64 + l;
        float x = qb[3*q], y = qb[3*q+1], z = qb[3*q+2];
        QX[s] = (v2f){ x, x };
        QY[s] = (v2f){ y, y };
        QZ[s] = (v2f){ z, z };
        MN[s] = (v2f){ FLT_MAX, FLT_MAX };
        if (w == 0) qw_s[q] = fmaf(x, x, fmaf(y, y, z * z));
    }
    __syncthreads();

    // Wave w scans pairs [w*64, w*64+64) from LDS (uniform-address broadcast).
    const v2f* lp = (const v2f*)buf + (size_t)(w * 64) * 4;
    #pragma unroll 4
    for (int j = 0; j < 64; ++j) {
        v2f RX = lp[4*j + 0];
        v2f RY = lp[4*j + 1];
        v2f RZ = lp[4*j + 2];
        v2f RW = lp[4*j + 3];
        #pragma unroll
        for (int s = 0; s < 8; ++s) {
            v2f a = __builtin_elementwise_fma(QX[s], RX, RW);
            a = __builtin_elementwise_fma(QY[s], RY, a);
            a = __builtin_elementwise_fma(QZ[s], RZ, a);
            MN[s] = __builtin_elementwise_min(MN[s], a);
        }
    }
    __syncthreads();                             // tile reads done; reuse buf

    // Combine the 4 wave-partials per query in LDS (buf reused as red[2048]).
    #pragma unroll
    for (int s = 0; s < 8; ++s)
        buf[(w << 9) + s * 64 + l] = fminf(MN[s].x, MN[s].y);
    __syncthreads();

    // part[dir][g][b][query]: plain coalesced stores, combined in hd_final.
    size_t dirOff = dir ? (size_t)GROUPS * B_CONST * N : 0;
    float* pb = part + dirOff + ((size_t)g * B_CONST + b) * QN + ((size_t)qblk << 9);
    for (int t = threadIdx.x; t < 512; t += 256) {
        float m = fminf(fminf(buf[t], buf[512 + t]),
                        fminf(buf[1024 + t], buf[1536 + t]));
        pb[t] = fmaxf(qw_s[t] + m, 0.0f);        // min over this ref group
    }
}

// 128 blocks: one per (dir, b, query-slice). min over GROUPS partials, max over
// the query slice, atomicMax into comm[b]; global ticket 127 sums into out[0].
// Cross-kernel visibility of `part`/`comm` is free (kernel-boundary ordering).
__global__ __launch_bounds__(256) void hd_final(
    const float* __restrict__ part, unsigned int* __restrict__ comm,
    float* __restrict__ out, int N, int M) {
    int db  = blockIdx.x >> 3;                  // 0..15
    int qs  = blockIdx.x & (QSPLIT - 1);
    int dir = db >> 3;
    int b   = db & 7;
    int QN  = dir ? M : N;
    size_t dirOff = dir ? (size_t)GROUPS * B_CONST * N : 0;
    const float* fb = part + dirOff + (size_t)b * QN;
    size_t gs = (size_t)B_CONST * QN;

    int span = QN / QSPLIT;
    int q0 = qs * span;
    float mx = 0.0f;
    for (int qq = q0 + threadIdx.x; qq < q0 + span; qq += 256) {
        float mm = fb[qq];
        #pragma unroll
        for (int gg = 1; gg < GROUPS; ++gg)
            mm = fminf(mm, fb[(size_t)gg * gs + qq]);
        mx = fmaxf(mx, mm);
    }
    #pragma unroll
    for (int off = 32; off > 0; off >>= 1)
        mx = fmaxf(mx, __shfl_down(mx, off, 64));
    __shared__ float wred[4];
    int l = threadIdx.x & 63, w = threadIdx.x >> 6;
    if (l == 0) wred[w] = mx;
    __syncthreads();
    if (threadIdx.x == 0) {
        mx = fmaxf(fmaxf(wred[0], wred[1]), fmaxf(wred[2], wred[3]));
        atomicMax(&comm[b], __float_as_uint(mx));   // covers both dirs + slices
        __threadfence();
        unsigned int t2 = atomicAdd(&comm[8], 1u);
        if (t2 == (unsigned int)(16 * QSPLIT - 1)) {
            float s = 0.0f;
            for (int bb = 0; bb < B_CONST; ++bb)
                s += __uint_as_float(atomicMax(&comm[bb], 0u));  // coherent read
            out[0] = s;
        }
    }
}

extern "C" void kernel_launch(void* const* d_in, const int* in_sizes, int n_in,
                              void* d_out, int out_size, void* d_ws, size_t ws_size,
                              hipStream_t stream) {
    const float* p1 = (const float*)d_in[0];
    const float* p2 = (const float*)d_in[1];
    const int B = B_CONST;
    int N = in_sizes[0] / (3 * B);
    int M = in_sizes[1] / (3 * B);
    int n1 = B * N, n2 = B * M;

    char* ws = (char*)d_ws;
    float* part = (float*)ws;                    // GROUPS*(n1+n2) floats = 2MB
    unsigned int* comm = (unsigned int*)(part + (size_t)GROUPS * (n1 + n2));

    int blocksDir0 = B * (N >> 9) * GROUPS;      // 512 per dir
    int blocksDir1 = B * (M >> 9) * GROUPS;
    hd_nnmax<<<blocksDir0 + blocksDir1, 256, 0, stream>>>(
        p1, p2, part, comm, N, M, blocksDir0);

    hd_final<<<16 * QSPLIT, 256, 0, stream>>>(part, comm, (float*)d_out, N, M);
}